// Round 5
// baseline (285.001 us; speedup 1.0000x reference)
//
#include <hip/hip_runtime.h>
#include <math.h>

#define D        128
#define KCODES   2048
#define NPTS     32768
#define AS       136          // halves per LDS code-row (128 + 8 pad)
#define LO_SCALE 4096.0f
#define CSLICES  4            // 4 x 512 codes
#define CODES_PER_SLICE 512
#define CHUNK    64           // codes staged per chunk
#define NCHUNK   (CODES_PER_SLICE / CHUNK)   // 8
#define PSLICES  (NPTS / 256)                // 128 blocks of 256 points
// s2 = s * log2e / T;  s = 2*dot - esq
#define C1       3.205988979753252f          // 2*log2e/T
#define C2       (C1 / LO_SCALE)
#define ESQ_SCALE 1.602994489876626f         // log2e/T

typedef _Float16 half8 __attribute__((ext_vector_type(8)));
typedef float    f32x4 __attribute__((ext_vector_type(4)));

// ---------------------------------------------------------------------------
// Prep: e_sqt[c] = ||e_c||^2 * log2e/T ; fp16 hi/lo split of embed (lo
// pre-scaled by 4096); zero classacc. One wave per code.
// ---------------------------------------------------------------------------
__global__ void prep_kernel(const float* __restrict__ embed,
                            float* __restrict__ e_sqt,
                            _Float16* __restrict__ e_hi,
                            _Float16* __restrict__ e_lo,
                            float* __restrict__ classacc) {
    const int c = blockIdx.x;
    const int t = threadIdx.x;  // 0..63
    float v0 = embed[(size_t)c * D + t];
    float v1 = embed[(size_t)c * D + 64 + t];
    _Float16 h0 = (_Float16)v0;
    _Float16 h1 = (_Float16)v1;
    e_hi[(size_t)c * D + t]      = h0;
    e_hi[(size_t)c * D + 64 + t] = h1;
    e_lo[(size_t)c * D + t]      = (_Float16)((v0 - (float)h0) * LO_SCALE);
    e_lo[(size_t)c * D + 64 + t] = (_Float16)((v1 - (float)h1) * LO_SCALE);
    float s = v0 * v0 + v1 * v1;
    #pragma unroll
    for (int off = 32; off > 0; off >>= 1) s += __shfl_down(s, off, 64);
    if (t == 0) {
        e_sqt[c] = s * ESQ_SCALE;
        classacc[c] = 0.0f;
    }
}

// stage one 64-code chunk of pre-split e_hi/e_lo into padded LDS (pure copy)
__device__ __forceinline__ void stage_e(const uint4* __restrict__ ehi_g4,
                                        const uint4* __restrict__ elo_g4,
                                        _Float16* ehi, _Float16* elo,
                                        int cbase, int tid) {
    #pragma unroll
    for (int it = 0; it < 4; ++it) {
        int j   = tid + it * 256;      // 0..1023 uint4 (64 rows x 16)
        int row = j >> 4;
        int c8  = j & 15;
        uint4 vh = ehi_g4[(size_t)cbase * 16 + j];
        uint4 vl = elo_g4[(size_t)cbase * 16 + j];
        *(uint4*)&ehi[row * AS + c8 * 8] = vh;
        *(uint4*)&elo[row * AS + c8 * 8] = vl;
    }
}

// load this lane's resident A fragments (64 points) from global x, split hi/lo
__device__ __forceinline__ void load_a(const float* __restrict__ x,
                                       int p0w, int col, int quad,
                                       half8 ahi[4][4], half8 alo[4][4]) {
    #pragma unroll
    for (int pt = 0; pt < 4; ++pt) {
        const float* xp = x + (size_t)(p0w + pt * 16 + col) * D + quad * 8;
        #pragma unroll
        for (int kk = 0; kk < 4; ++kk) {
            #pragma unroll
            for (int j = 0; j < 8; ++j) {
                float v = xp[kk * 32 + j];
                _Float16 h = (_Float16)v;
                ahi[pt][kk][j] = h;
                alo[pt][kk][j] = (_Float16)((v - (float)h) * LO_SCALE);
            }
        }
    }
}

// ---------------------------------------------------------------------------
// Sweep A (point-resident): wave holds 64 points' A-frags + softmax state in
// registers; streams 512 codes through LDS. Per-point state reduced ONCE at
// the end. Writes partials pm/pl/pidx [CSLICES][NPTS].
// ---------------------------------------------------------------------------
__global__ __launch_bounds__(256, 2)
void sweepA_kernel(const float* __restrict__ x,
                   const _Float16* __restrict__ e_hi_g,
                   const _Float16* __restrict__ e_lo_g,
                   const float* __restrict__ e_sqt_g,
                   float* __restrict__ pm, float* __restrict__ pl,
                   int* __restrict__ pidx) {
    __shared__ _Float16 ehi[CHUNK * AS];   // 17.4 KB
    __shared__ _Float16 elo[CHUNK * AS];   // 17.4 KB
    __shared__ float esq_s[CODES_PER_SLICE];

    const int tid  = threadIdx.x;
    const int w    = tid >> 6;
    const int lane = tid & 63;
    const int col  = lane & 15;
    const int quad = lane >> 4;
    const int cslice = blockIdx.y;
    const int c0   = cslice * CODES_PER_SLICE;
    const int p0w  = blockIdx.x * 256 + w * 64;

    for (int i = tid; i < CODES_PER_SLICE; i += 256) esq_s[i] = e_sqt_g[c0 + i];

    half8 ahi[4][4], alo[4][4];
    load_a(x, p0w, col, quad, ahi, alo);

    const uint4* ehi_g4 = (const uint4*)e_hi_g;
    const uint4* elo_g4 = (const uint4*)e_lo_g;

    float lrun[4][4], bv[4][4];
    int   bi[4][4];
    #pragma unroll
    for (int pt = 0; pt < 4; ++pt)
        #pragma unroll
        for (int r = 0; r < 4; ++r) { lrun[pt][r] = 0.f; bv[pt][r] = -INFINITY; bi[pt][r] = 0; }

    for (int chunk = 0; chunk < NCHUNK; ++chunk) {
        const int cbase = c0 + chunk * CHUNK;
        __syncthreads();
        stage_e(ehi_g4, elo_g4, ehi, elo, cbase, tid);
        __syncthreads();

        #pragma unroll
        for (int ct = 0; ct < 4; ++ct) {
            f32x4 chh[4], cx[4];
            #pragma unroll
            for (int pt = 0; pt < 4; ++pt) { chh[pt] = (f32x4){0,0,0,0}; cx[pt] = (f32x4){0,0,0,0}; }
            #pragma unroll
            for (int kk = 0; kk < 4; ++kk) {
                const int boff = (ct * 16 + col) * AS + kk * 32 + quad * 8;
                half8 Bhi = *(const half8*)&ehi[boff];
                half8 Blo = *(const half8*)&elo[boff];
                #pragma unroll
                for (int pt = 0; pt < 4; ++pt) {
                    chh[pt] = __builtin_amdgcn_mfma_f32_16x16x32_f16(ahi[pt][kk], Bhi, chh[pt], 0, 0, 0);
                    cx[pt]  = __builtin_amdgcn_mfma_f32_16x16x32_f16(ahi[pt][kk], Blo, cx[pt], 0, 0, 0);
                    cx[pt]  = __builtin_amdgcn_mfma_f32_16x16x32_f16(alo[pt][kk], Bhi, cx[pt], 0, 0, 0);
                }
            }
            const int code = chunk * CHUNK + ct * 16 + col;     // within slice
            const float esqT = esq_s[code];
            const int gcode = c0 + code;
            #pragma unroll
            for (int pt = 0; pt < 4; ++pt) {
                #pragma unroll
                for (int r = 0; r < 4; ++r) {
                    float s2 = fmaf(chh[pt][r], C1, fmaf(cx[pt][r], C2, -esqT));
                    lrun[pt][r] += exp2f(s2);
                    if (s2 > bv[pt][r]) { bv[pt][r] = s2; bi[pt][r] = gcode; }
                }
            }
        }
    }

    // once-per-kernel reduction across the 16 cols
    #pragma unroll
    for (int pt = 0; pt < 4; ++pt) {
        #pragma unroll
        for (int r = 0; r < 4; ++r) {
            float v = bv[pt][r]; int idx = bi[pt][r]; float l = lrun[pt][r];
            #pragma unroll
            for (int off = 8; off >= 1; off >>= 1) {
                float ov = __shfl_xor(v, off, 16);
                int   oi = __shfl_xor(idx, off, 16);
                float ol = __shfl_xor(l, off, 16);
                l += ol;
                if (ov > v || (ov == v && oi < idx)) { v = ov; idx = oi; }
            }
            if (col == 0) {
                size_t o = (size_t)cslice * NPTS + p0w + pt * 16 + quad * 4 + r;
                pm[o] = v; pl[o] = l; pidx[o] = idx;
            }
        }
    }
}

// ---------------------------------------------------------------------------
// Combine: per point, reduce CSLICES partials -> r=1/sum(l), argmax.
// ---------------------------------------------------------------------------
__global__ void combine_kernel(const float* __restrict__ pm, const float* __restrict__ pl,
                               const int* __restrict__ pidx,
                               float* __restrict__ r_buf, int* __restrict__ idx_buf,
                               float* __restrict__ ind_out) {
    const int p = blockIdx.x * 256 + threadIdx.x;
    float bm = -INFINITY; int bi = 0; float l = 0.0f;
    #pragma unroll
    for (int sl = 0; sl < CSLICES; ++sl) {   // slices ascend in code
        size_t o = (size_t)sl * NPTS + p;
        float v = pm[o];
        l += pl[o];
        if (v > bm) { bm = v; bi = pidx[o]; }
    }
    r_buf[p] = 1.0f / l;
    idx_buf[p] = bi;
    ind_out[p] = (float)bi;
}

// ---------------------------------------------------------------------------
// Sweep B (point-resident): class accumulation. Per chunk/ct: 2 shuffles +
// one LDS atomic per active lane; block flushes its 512 bins once.
// ---------------------------------------------------------------------------
__global__ __launch_bounds__(256, 2)
void sweepB_kernel(const float* __restrict__ x,
                   const _Float16* __restrict__ e_hi_g,
                   const _Float16* __restrict__ e_lo_g,
                   const float* __restrict__ e_sqt_g,
                   const float* __restrict__ r_buf,
                   float* __restrict__ classacc) {
    __shared__ _Float16 ehi[CHUNK * AS];
    __shared__ _Float16 elo[CHUNK * AS];
    __shared__ float esq_s[CODES_PER_SLICE];
    __shared__ float bins[CODES_PER_SLICE];

    const int tid  = threadIdx.x;
    const int w    = tid >> 6;
    const int lane = tid & 63;
    const int col  = lane & 15;
    const int quad = lane >> 4;
    const int cslice = blockIdx.y;
    const int c0   = cslice * CODES_PER_SLICE;
    const int p0w  = blockIdx.x * 256 + w * 64;

    for (int i = tid; i < CODES_PER_SLICE; i += 256) {
        esq_s[i] = e_sqt_g[c0 + i];
        bins[i] = 0.0f;
    }

    half8 ahi[4][4], alo[4][4];
    load_a(x, p0w, col, quad, ahi, alo);

    float rr[4][4];
    #pragma unroll
    for (int pt = 0; pt < 4; ++pt)
        #pragma unroll
        for (int r = 0; r < 4; ++r)
            rr[pt][r] = r_buf[p0w + pt * 16 + quad * 4 + r];

    const uint4* ehi_g4 = (const uint4*)e_hi_g;
    const uint4* elo_g4 = (const uint4*)e_lo_g;

    for (int chunk = 0; chunk < NCHUNK; ++chunk) {
        const int cbase = c0 + chunk * CHUNK;
        __syncthreads();
        stage_e(ehi_g4, elo_g4, ehi, elo, cbase, tid);
        __syncthreads();

        #pragma unroll
        for (int ct = 0; ct < 4; ++ct) {
            f32x4 chh[4], cx[4];
            #pragma unroll
            for (int pt = 0; pt < 4; ++pt) { chh[pt] = (f32x4){0,0,0,0}; cx[pt] = (f32x4){0,0,0,0}; }
            #pragma unroll
            for (int kk = 0; kk < 4; ++kk) {
                const int boff = (ct * 16 + col) * AS + kk * 32 + quad * 8;
                half8 Bhi = *(const half8*)&ehi[boff];
                half8 Blo = *(const half8*)&elo[boff];
                #pragma unroll
                for (int pt = 0; pt < 4; ++pt) {
                    chh[pt] = __builtin_amdgcn_mfma_f32_16x16x32_f16(ahi[pt][kk], Bhi, chh[pt], 0, 0, 0);
                    cx[pt]  = __builtin_amdgcn_mfma_f32_16x16x32_f16(ahi[pt][kk], Blo, cx[pt], 0, 0, 0);
                    cx[pt]  = __builtin_amdgcn_mfma_f32_16x16x32_f16(alo[pt][kk], Bhi, cx[pt], 0, 0, 0);
                }
            }
            const int code = chunk * CHUNK + ct * 16 + col;     // within slice
            const float esqT = esq_s[code];
            float wsum = 0.0f;
            #pragma unroll
            for (int pt = 0; pt < 4; ++pt) {
                #pragma unroll
                for (int r = 0; r < 4; ++r) {
                    float s2 = fmaf(chh[pt][r], C1, fmaf(cx[pt][r], C2, -esqT));
                    wsum += exp2f(s2) * rr[pt][r];
                }
            }
            wsum += __shfl_xor(wsum, 16, 64);   // sum quads (same code col)
            wsum += __shfl_xor(wsum, 32, 64);
            if (quad == 0) atomicAdd(&bins[code], wsum);
        }
    }

    __syncthreads();
    for (int i = tid; i < CODES_PER_SLICE; i += 256)
        atomicAdd(&classacc[c0 + i], bins[i]);
}

// ---------------------------------------------------------------------------
__global__ void gather_kernel(const float* __restrict__ embed,
                              const int* __restrict__ idx_buf,
                              float* __restrict__ q_out) {
    const int j = blockIdx.x * 256 + threadIdx.x;   // one float4 each
    const int row = j >> 5;
    const int d4 = j & 31;
    reinterpret_cast<float4*>(q_out)[(size_t)row * 32 + d4] =
        reinterpret_cast<const float4*>(embed)[(size_t)idx_buf[row] * 32 + d4];
}

// ---------------------------------------------------------------------------
__global__ void finalize_kernel(const float* __restrict__ classacc,
                                float* __restrict__ loss_out, int N, int K) {
    __shared__ float red[256];
    const int tid = threadIdx.x;
    float s = 0.0f;
    const float invN = 1.0f / (float)N;
    for (int i = tid; i < K; i += 256) {
        float cp = classacc[i] * invN;
        s += cp * logf(cp + 1e-6f);
    }
    red[tid] = s;
    __syncthreads();
    for (int off = 128; off > 0; off >>= 1) {
        if (tid < off) red[tid] += red[tid + off];
        __syncthreads();
    }
    if (tid == 0) loss_out[0] = red[0];
}

extern "C" void kernel_launch(void* const* d_in, const int* in_sizes, int n_in,
                              void* d_out, int out_size, void* d_ws, size_t ws_size,
                              hipStream_t stream) {
    const float* x     = (const float*)d_in[0];
    const float* embed = (const float*)d_in[1];

    float* out      = (float*)d_out;
    float* q_out    = out;
    float* ind_out  = out + (size_t)NPTS * D;
    float* loss_out = ind_out + NPTS;

    float*    e_sqt = (float*)d_ws;                        // K
    float*    cacc  = e_sqt + KCODES;                      // K
    _Float16* e_hi  = (_Float16*)(cacc + KCODES);          // K*D halves
    _Float16* e_lo  = e_hi + (size_t)KCODES * D;           // K*D halves
    float*    pm    = (float*)(e_lo + (size_t)KCODES * D); // CSLICES*N
    float*    pl    = pm + (size_t)CSLICES * NPTS;         // CSLICES*N
    int*      pidx  = (int*)(pl + (size_t)CSLICES * NPTS); // CSLICES*N
    float*    r_buf = (float*)(pidx + (size_t)CSLICES * NPTS); // N
    int*      idx_buf = (int*)(r_buf + NPTS);              // N

    dim3 sgrid(PSLICES, CSLICES);

    prep_kernel<<<KCODES, 64, 0, stream>>>(embed, e_sqt, e_hi, e_lo, cacc);
    sweepA_kernel<<<sgrid, 256, 0, stream>>>(x, e_hi, e_lo, e_sqt, pm, pl, pidx);
    combine_kernel<<<NPTS / 256, 256, 0, stream>>>(pm, pl, pidx, r_buf, idx_buf, ind_out);
    sweepB_kernel<<<sgrid, 256, 0, stream>>>(x, e_hi, e_lo, e_sqt, r_buf, cacc);
    gather_kernel<<<NPTS * 32 / 256, 256, 0, stream>>>(embed, idx_buf, q_out);
    finalize_kernel<<<1, 256, 0, stream>>>(cacc, loss_out, NPTS, KCODES);
}

// Round 6
// 203.059 us; speedup vs baseline: 1.4035x; 1.4035x over previous
//
#include <hip/hip_runtime.h>
#include <math.h>

#define D        128
#define KCODES   2048
#define NPTS     32768
#define LO_SCALE 4096.0f
// exp2-domain: s2 = (2*dot - e^2) * log2e / T
#define C1       3.205988979753252f          // 2*log2e/T
#define C2       (C1 / LO_SCALE)
#define ESQ_SCALE 1.602994489876626f         // log2e/T

// sweepA: point-resident, 32 pts/wave, 128 pts/block, 2 code slices of 1024
#define A_CSLICES 2
#define A_CODES   1024
#define A_NCH     (A_CODES / 64)             // 16 chunks of 64 codes
// sweepB: code-resident, 64 codes/wave, 256 codes/block (8 slices), 512 pts/block
#define B_CSLICES 8
#define B_NCH     8                          // 8 chunks of 64 points

// swizzle: logical 16B-group G of row r stored at slot SW(G,r)
#define SW(G, r)  (((G) & 8) | (((G) ^ (r)) & 7))

typedef _Float16 half8 __attribute__((ext_vector_type(8)));
typedef float    f32x4 __attribute__((ext_vector_type(4)));

// ---------------------------------------------------------------------------
// Prep: fp16 hi/lo split (lo pre-scaled by 4096) into XOR-swizzled rows.
// 4 threads per row, 64 rows per block.
// ---------------------------------------------------------------------------
__device__ __forceinline__ void split_row_part(const float* __restrict__ src,
                                               _Float16* __restrict__ hi_row,
                                               _Float16* __restrict__ lo_row,
                                               int part, int rkey, float* ss) {
    #pragma unroll
    for (int g = 0; g < 4; ++g) {
        const int G = part * 4 + g;
        half8 h, l;
        float s = 0.0f;
        #pragma unroll
        for (int j = 0; j < 8; ++j) {
            float v = src[g * 8 + j];
            _Float16 hh = (_Float16)v;
            h[j] = hh;
            l[j] = (_Float16)((v - (float)hh) * LO_SCALE);
            s += v * v;
        }
        *ss += s;
        const int slot = SW(G, rkey);
        *(half8*)(hi_row + slot * 8) = h;
        *(half8*)(lo_row + slot * 8) = l;
    }
}

__global__ void prep_e_kernel(const float* __restrict__ embed,
                              float* __restrict__ e_sqt,
                              _Float16* __restrict__ ehi, _Float16* __restrict__ elo,
                              float* __restrict__ cacc) {
    const int tid = threadIdx.x;
    const int row = blockIdx.x * 64 + (tid >> 2);
    const int part = tid & 3;
    float ss = 0.0f;
    split_row_part(embed + (size_t)row * D + part * 32,
                   ehi + (size_t)row * D, elo + (size_t)row * D, part, row & 7, &ss);
    ss += __shfl_xor(ss, 1, 64);
    ss += __shfl_xor(ss, 2, 64);
    if (part == 0) e_sqt[row] = ss * ESQ_SCALE;
    if (part == 1) cacc[row] = 0.0f;
}

__global__ void prep_x_kernel(const float* __restrict__ x,
                              _Float16* __restrict__ xhi, _Float16* __restrict__ xlo) {
    const int tid = threadIdx.x;
    const int row = blockIdx.x * 64 + (tid >> 2);
    const int part = tid & 3;
    float ss = 0.0f;
    split_row_part(x + (size_t)row * D + part * 32,
                   xhi + (size_t)row * D, xlo + (size_t)row * D, part, row & 7, &ss);
}

// async DMA of one 64-row chunk (16 rows per wave, 256 B/row) into LDS
__device__ __forceinline__ void dma_rows(const _Float16* __restrict__ g_base,
                                         _Float16* lds_base, int row0, int w, int lane) {
    const char* src = (const char*)g_base + (size_t)(row0 + 16 * w) * 256 + lane * 16;
    char* dst = (char*)lds_base + 16 * w * 256;
    #pragma unroll
    for (int i = 0; i < 4; ++i) {
        __builtin_amdgcn_global_load_lds(
            (const __attribute__((address_space(1))) unsigned int*)(src + i * 1024),
            (__attribute__((address_space(3))) unsigned int*)(dst + i * 1024),
            16, 0, 0);
    }
}

// ---------------------------------------------------------------------------
// Sweep A: point-resident (32 pts/wave in regs), codes stream via dbuf LDS.
// Softmax/argmax state in registers, flushed once. Partials [2][NPTS].
// ---------------------------------------------------------------------------
__global__ __launch_bounds__(256, 2)
void sweepA_kernel(const _Float16* __restrict__ xhi_g, const _Float16* __restrict__ xlo_g,
                   const _Float16* __restrict__ ehi_g, const _Float16* __restrict__ elo_g,
                   const float* __restrict__ e_sqt_g,
                   float* __restrict__ pm, float* __restrict__ pl, int* __restrict__ pidx) {
    __shared__ _Float16 EHI[2][64 * D];   // 2 x 16 KB
    __shared__ _Float16 ELO[2][64 * D];   // 2 x 16 KB
    __shared__ float esq_s[A_CODES];      // 4 KB

    const int tid  = threadIdx.x;
    const int w    = tid >> 6;
    const int lane = tid & 63;
    const int col  = lane & 15;
    const int quad = lane >> 4;
    const int c0   = blockIdx.y * A_CODES;
    const int p0w  = blockIdx.x * 128 + w * 32;

    // prefetch chunk 0 + stage esq
    dma_rows(ehi_g, EHI[0], c0, w, lane);
    dma_rows(elo_g, ELO[0], c0, w, lane);
    for (int i = tid; i < A_CODES; i += 256) esq_s[i] = e_sqt_g[c0 + i];

    // resident A fragments (2 point-tiles x 4 k-steps), swizzled direct loads
    half8 ahi[2][4], alo[2][4];
    #pragma unroll
    for (int pt = 0; pt < 2; ++pt) {
        const int pr = p0w + pt * 16 + col;          // pr & 7 == col & 7
        #pragma unroll
        for (int kk = 0; kk < 4; ++kk) {
            const int slot = SW(kk * 4 + quad, col & 7);
            ahi[pt][kk] = *(const half8*)(xhi_g + (size_t)pr * D + slot * 8);
            alo[pt][kk] = *(const half8*)(xlo_g + (size_t)pr * D + slot * 8);
        }
    }

    float lrun[2][4], bv[2][4];
    int   bi[2][4];
    #pragma unroll
    for (int pt = 0; pt < 2; ++pt)
        #pragma unroll
        for (int r = 0; r < 4; ++r) { lrun[pt][r] = 0.f; bv[pt][r] = -INFINITY; bi[pt][r] = 0; }

    __syncthreads();   // chunk0 DMA + esq ready

    for (int ch = 0; ch < A_NCH; ++ch) {
        const int cur = ch & 1;
        if (ch + 1 < A_NCH) {
            dma_rows(ehi_g, EHI[cur ^ 1], c0 + (ch + 1) * 64, w, lane);
            dma_rows(elo_g, ELO[cur ^ 1], c0 + (ch + 1) * 64, w, lane);
        }
        const _Float16* ehi = EHI[cur];
        const _Float16* elo = ELO[cur];

        #pragma unroll
        for (int ct = 0; ct < 4; ++ct) {
            f32x4 chh[2], cx[2];
            #pragma unroll
            for (int pt = 0; pt < 2; ++pt) { chh[pt] = (f32x4){0,0,0,0}; cx[pt] = (f32x4){0,0,0,0}; }
            #pragma unroll
            for (int kk = 0; kk < 4; ++kk) {
                const int boff = (ct * 16 + col) * D + SW(kk * 4 + quad, col & 7) * 8;
                half8 Bhi = *(const half8*)&ehi[boff];
                half8 Blo = *(const half8*)&elo[boff];
                #pragma unroll
                for (int pt = 0; pt < 2; ++pt) {
                    chh[pt] = __builtin_amdgcn_mfma_f32_16x16x32_f16(ahi[pt][kk], Bhi, chh[pt], 0, 0, 0);
                    cx[pt]  = __builtin_amdgcn_mfma_f32_16x16x32_f16(ahi[pt][kk], Blo, cx[pt], 0, 0, 0);
                    cx[pt]  = __builtin_amdgcn_mfma_f32_16x16x32_f16(alo[pt][kk], Bhi, cx[pt], 0, 0, 0);
                }
            }
            const int lcode = ch * 64 + ct * 16 + col;
            const float esqT = esq_s[lcode];
            const int gcode = c0 + lcode;
            #pragma unroll
            for (int pt = 0; pt < 2; ++pt) {
                #pragma unroll
                for (int r = 0; r < 4; ++r) {
                    float s2 = fmaf(chh[pt][r], C1, fmaf(cx[pt][r], C2, -esqT));
                    lrun[pt][r] += exp2f(s2);
                    if (s2 > bv[pt][r]) { bv[pt][r] = s2; bi[pt][r] = gcode; }  // codes ascend
                }
            }
        }
        __syncthreads();   // drains next-chunk DMA; guards buffer reuse
    }

    // once-per-kernel 16-col reduction + partial write
    #pragma unroll
    for (int pt = 0; pt < 2; ++pt) {
        #pragma unroll
        for (int r = 0; r < 4; ++r) {
            float v = bv[pt][r]; int idx = bi[pt][r]; float l = lrun[pt][r];
            #pragma unroll
            for (int off = 8; off >= 1; off >>= 1) {
                float ov = __shfl_xor(v, off, 16);
                int   oi = __shfl_xor(idx, off, 16);
                float ol = __shfl_xor(l, off, 16);
                l += ol;
                if (ov > v || (ov == v && oi < idx)) { v = ov; idx = oi; }
            }
            if (col == 0) {
                size_t o = (size_t)blockIdx.y * NPTS + p0w + pt * 16 + quad * 4 + r;
                pm[o] = v; pl[o] = l; pidx[o] = idx;
            }
        }
    }
}

// ---------------------------------------------------------------------------
// Combine: per point, reduce 2 code-slice partials -> r=1/sum(l), argmax.
// ---------------------------------------------------------------------------
__global__ void combine_kernel(const float* __restrict__ pm, const float* __restrict__ pl,
                               const int* __restrict__ pidx,
                               float* __restrict__ r_buf, int* __restrict__ idx_buf,
                               float* __restrict__ ind_out) {
    const int p = blockIdx.x * 256 + threadIdx.x;
    float bm = -INFINITY; int bi = 0; float l = 0.0f;
    #pragma unroll
    for (int sl = 0; sl < A_CSLICES; ++sl) {   // slices ascend in code
        size_t o = (size_t)sl * NPTS + p;
        float v = pm[o];
        l += pl[o];
        if (v > bm) { bm = v; bi = pidx[o]; }
    }
    r_buf[p] = 1.0f / l;
    idx_buf[p] = bi;
    ind_out[p] = (float)bi;
}

// ---------------------------------------------------------------------------
// Sweep B: code-resident (64 codes/wave in regs), points stream via dbuf LDS.
// Per-code sums persist in registers; one global atomic per code per wave.
// ---------------------------------------------------------------------------
__global__ __launch_bounds__(256, 2)
void sweepB_kernel(const _Float16* __restrict__ xhi_g, const _Float16* __restrict__ xlo_g,
                   const _Float16* __restrict__ ehi_g, const _Float16* __restrict__ elo_g,
                   const float* __restrict__ e_sqt_g, const float* __restrict__ r_buf,
                   float* __restrict__ classacc) {
    __shared__ _Float16 XHI[2][64 * D];   // 2 x 16 KB
    __shared__ _Float16 XLO[2][64 * D];   // 2 x 16 KB
    __shared__ float rs[2][64];

    const int tid  = threadIdx.x;
    const int w    = tid >> 6;
    const int lane = tid & 63;
    const int col  = lane & 15;
    const int quad = lane >> 4;
    const int pbase0 = blockIdx.x * (64 * B_NCH);
    const int c0w  = blockIdx.y * 256 + w * 64;

    // prefetch chunk 0
    dma_rows(xhi_g, XHI[0], pbase0, w, lane);
    dma_rows(xlo_g, XLO[0], pbase0, w, lane);
    if (tid < 64) rs[0][tid] = r_buf[pbase0 + tid];

    // resident B fragments + scaled e_sq for this wave's 64 codes
    half8 bhi[4][4], blo[4][4];
    float esq_r[4];
    #pragma unroll
    for (int ct = 0; ct < 4; ++ct) {
        const int cr = c0w + ct * 16 + col;          // cr & 7 == col & 7
        esq_r[ct] = e_sqt_g[cr];
        #pragma unroll
        for (int kk = 0; kk < 4; ++kk) {
            const int slot = SW(kk * 4 + quad, col & 7);
            bhi[ct][kk] = *(const half8*)(ehi_g + (size_t)cr * D + slot * 8);
            blo[ct][kk] = *(const half8*)(elo_g + (size_t)cr * D + slot * 8);
        }
    }

    float csum[4] = {0.f, 0.f, 0.f, 0.f};
    __syncthreads();

    for (int ch = 0; ch < B_NCH; ++ch) {
        const int cur = ch & 1;
        if (ch + 1 < B_NCH) {
            dma_rows(xhi_g, XHI[cur ^ 1], pbase0 + (ch + 1) * 64, w, lane);
            dma_rows(xlo_g, XLO[cur ^ 1], pbase0 + (ch + 1) * 64, w, lane);
            if (tid < 64) rs[cur ^ 1][tid] = r_buf[pbase0 + (ch + 1) * 64 + tid];
        }
        const _Float16* xhi = XHI[cur];
        const _Float16* xlo = XLO[cur];

        #pragma unroll
        for (int p = 0; p < 4; ++p) {
            f32x4 chh[4], cx[4];
            #pragma unroll
            for (int ct = 0; ct < 4; ++ct) { chh[ct] = (f32x4){0,0,0,0}; cx[ct] = (f32x4){0,0,0,0}; }
            #pragma unroll
            for (int kk = 0; kk < 4; ++kk) {
                const int aoff = (p * 16 + col) * D + SW(kk * 4 + quad, col & 7) * 8;
                half8 Ahi = *(const half8*)&xhi[aoff];
                half8 Alo = *(const half8*)&xlo[aoff];
                #pragma unroll
                for (int ct = 0; ct < 4; ++ct) {
                    chh[ct] = __builtin_amdgcn_mfma_f32_16x16x32_f16(Ahi, bhi[ct][kk], chh[ct], 0, 0, 0);
                    cx[ct]  = __builtin_amdgcn_mfma_f32_16x16x32_f16(Ahi, blo[ct][kk], cx[ct], 0, 0, 0);
                    cx[ct]  = __builtin_amdgcn_mfma_f32_16x16x32_f16(Alo, bhi[ct][kk], cx[ct], 0, 0, 0);
                }
            }
            const f32x4 rr = *(const f32x4*)&rs[cur][p * 16 + quad * 4];
            #pragma unroll
            for (int ct = 0; ct < 4; ++ct) {
                #pragma unroll
                for (int r = 0; r < 4; ++r) {
                    float s2 = fmaf(chh[ct][r], C1, fmaf(cx[ct][r], C2, -esq_r[ct]));
                    csum[ct] += exp2f(s2) * rr[r];
                }
            }
        }
        __syncthreads();
    }

    #pragma unroll
    for (int ct = 0; ct < 4; ++ct) {
        float v = csum[ct];
        v += __shfl_xor(v, 16, 64);
        v += __shfl_xor(v, 32, 64);
        if (quad == 0) atomicAdd(&classacc[c0w + ct * 16 + col], v);
    }
}

// ---------------------------------------------------------------------------
__global__ void gather_kernel(const float* __restrict__ embed,
                              const int* __restrict__ idx_buf,
                              float* __restrict__ q_out) {
    const int j = blockIdx.x * 256 + threadIdx.x;
    const int row = j >> 5;
    const int d4 = j & 31;
    reinterpret_cast<float4*>(q_out)[(size_t)row * 32 + d4] =
        reinterpret_cast<const float4*>(embed)[(size_t)idx_buf[row] * 32 + d4];
}

__global__ void finalize_kernel(const float* __restrict__ classacc,
                                float* __restrict__ loss_out, int N, int K) {
    __shared__ float red[256];
    const int tid = threadIdx.x;
    float s = 0.0f;
    const float invN = 1.0f / (float)N;
    for (int i = tid; i < K; i += 256) {
        float cp = classacc[i] * invN;
        s += cp * logf(cp + 1e-6f);
    }
    red[tid] = s;
    __syncthreads();
    for (int off = 128; off > 0; off >>= 1) {
        if (tid < off) red[tid] += red[tid + off];
        __syncthreads();
    }
    if (tid == 0) loss_out[0] = red[0];
}

extern "C" void kernel_launch(void* const* d_in, const int* in_sizes, int n_in,
                              void* d_out, int out_size, void* d_ws, size_t ws_size,
                              hipStream_t stream) {
    const float* x     = (const float*)d_in[0];
    const float* embed = (const float*)d_in[1];

    float* out      = (float*)d_out;
    float* q_out    = out;
    float* ind_out  = out + (size_t)NPTS * D;
    float* loss_out = ind_out + NPTS;

    float*    e_sqt = (float*)d_ws;                          // 2048 f
    float*    cacc  = e_sqt + KCODES;                        // 2048 f
    _Float16* ehi   = (_Float16*)(cacc + KCODES);            // K*D halves (swizzled)
    _Float16* elo   = ehi + (size_t)KCODES * D;
    _Float16* xhi   = elo + (size_t)KCODES * D;              // N*D halves (swizzled)
    _Float16* xlo   = xhi + (size_t)NPTS * D;
    float*    pm    = (float*)(xlo + (size_t)NPTS * D);      // 2*N
    float*    pl    = pm + (size_t)A_CSLICES * NPTS;         // 2*N
    int*      pidx  = (int*)(pl + (size_t)A_CSLICES * NPTS); // 2*N
    float*    r_buf = (float*)(pidx + (size_t)A_CSLICES * NPTS); // N
    int*      idx_buf = (int*)(r_buf + NPTS);                // N

    prep_e_kernel<<<KCODES / 64, 256, 0, stream>>>(embed, e_sqt, ehi, elo, cacc);
    prep_x_kernel<<<NPTS / 64, 256, 0, stream>>>(x, xhi, xlo);
    sweepA_kernel<<<dim3(NPTS / 128, A_CSLICES), 256, 0, stream>>>(
        xhi, xlo, ehi, elo, e_sqt, pm, pl, pidx);
    combine_kernel<<<NPTS / 256, 256, 0, stream>>>(pm, pl, pidx, r_buf, idx_buf, ind_out);
    sweepB_kernel<<<dim3(NPTS / 512, B_CSLICES), 256, 0, stream>>>(
        xhi, xlo, ehi, elo, e_sqt, r_buf, cacc);
    gather_kernel<<<NPTS * 32 / 256, 256, 0, stream>>>(embed, idx_buf, q_out);
    finalize_kernel<<<1, 256, 0, stream>>>(cacc, loss_out, NPTS, KCODES);
}